// Round 2
// baseline (2334.048 us; speedup 1.0000x reference)
//
#include <hip/hip_runtime.h>
#include <hip/hip_bf16.h>

#define N 4096
#define D 64
#define NH 4
#define NSTEP 4

typedef short bf16x8 __attribute__((ext_vector_type(8)));
typedef float f32x4 __attribute__((ext_vector_type(4)));
typedef __hip_bfloat16 bf16;

// ws layout (bytes)
static const size_t OFF_MASK = 0;                              // NSTEP*N*128 u32 = 8 MB
static const size_t OFF_FEAT = (size_t)8 << 20;                // N*D f32 = 1 MB
static const size_t OFF_HNHI = (size_t)9 << 20;                // NH*N*D bf16 = 2 MB
static const size_t OFF_HNLO = (size_t)11 << 20;               // 2 MB
static const size_t OFF_HTHI = (size_t)13 << 20;               // 2 MB
static const size_t OFF_HTLO = (size_t)15 << 20;               // 2 MB
static const size_t OFF_HOUT = (size_t)17 << 20;               // NH*N*D f32 = 4 MB
static const size_t OFF_CM   = (size_t)21 << 20;               // NH*D f32

// one wave packs one row (4096 ints -> 128 u32 of bits), rows = NSTEP*N
__global__ void k_packadj(const int* __restrict__ adj, unsigned int* __restrict__ mw) {
    int wid = blockIdx.x * 4 + (threadIdx.x >> 6);
    int lane = threadIdx.x & 63;
    const int* rowp = adj + (size_t)wid * N;
    unsigned long long* out = (unsigned long long*)(mw + (size_t)wid * 128);
    for (int i = 0; i < 64; ++i) {
        int v = rowp[i * 64 + lane];
        unsigned long long b = __ballot(v > 0);
        if (lane == 0) out[i] = b;
    }
}

// h = X @ W[head] in fp32; emit hi/lo bf16 splits of hn (row-normalized) and of h (transposed);
// accumulate per-head column mean of h (fp32) for the empty-keep fallback.
__global__ void k_phase0(const float* __restrict__ X, const float* __restrict__ W,
                         bf16* __restrict__ hnhi, bf16* __restrict__ hnlo,
                         bf16* __restrict__ hthi, bf16* __restrict__ htlo,
                         float* __restrict__ colmean) {
    __shared__ float Xs[64][65];
    __shared__ float Wsh[64][64];
    __shared__ float colsum[64];
    int head = blockIdx.y;
    int r0 = blockIdx.x * 64;
    int t = threadIdx.x;
    for (int i = 0; i < 16; ++i) {
        int idx = t + 256 * i;
        int r = idx >> 6, c = idx & 63;
        Xs[r][c] = X[(size_t)(r0 + r) * 64 + c];
        Wsh[r][c] = W[(size_t)head * 4096 + idx];
    }
    if (t < 64) colsum[t] = 0.f;
    __syncthreads();
    int lane = t & 63, w = t >> 6;
    int lr = w * 16 + (lane >> 2);
    int e0 = (lane & 3) * 16;
    float acc[16];
#pragma unroll
    for (int j = 0; j < 16; ++j) acc[j] = 0.f;
    for (int d = 0; d < 64; ++d) {
        float xv = Xs[lr][d];
#pragma unroll
        for (int j = 0; j < 16; ++j) acc[j] = fmaf(xv, Wsh[d][e0 + j], acc[j]);
    }
    float ss = 0.f;
#pragma unroll
    for (int j = 0; j < 16; ++j) ss = fmaf(acc[j], acc[j], ss);
    ss += __shfl_xor(ss, 1, 64);
    ss += __shfl_xor(ss, 2, 64);
    float rn = 1.0f / (sqrtf(ss) + 1e-12f);
    int row = r0 + lr;
#pragma unroll
    for (int j = 0; j < 16; ++j) {
        float hv = acc[j];
        bf16 hhi = __float2bfloat16(hv);
        bf16 hlo = __float2bfloat16(hv - __bfloat162float(hhi));
        size_t tidx = (size_t)head * N * 64 + (size_t)(e0 + j) * N + row;
        hthi[tidx] = hhi;
        htlo[tidx] = hlo;
        float hnv = hv * rn;
        bf16 nhi = __float2bfloat16(hnv);
        bf16 nlo = __float2bfloat16(hnv - __bfloat162float(nhi));
        size_t nidx = ((size_t)head * N + row) * 64 + e0 + j;
        hnhi[nidx] = nhi;
        hnlo[nidx] = nlo;
    }
#pragma unroll
    for (int j = 0; j < 16; ++j) {
        float v = acc[j];
        v += __shfl_xor(v, 4, 64);
        v += __shfl_xor(v, 8, 64);
        v += __shfl_xor(v, 16, 64);
        v += __shfl_xor(v, 32, 64);
        if ((lane >> 2) == 0) atomicAdd(&colsum[e0 + j], v);
    }
    __syncthreads();
    if (t < 64) atomicAdd(&colmean[head * 64 + t], colsum[t] * (1.0f / N));
}

// split-bf16 sim tile: s = hi*hi + lo*hi + hi*lo (fp32 accumulate). Shared by pass A and B
// so the keep rule compares bit-identical values.
__device__ __forceinline__ f32x4 sim_tile(const bf16* __restrict__ hi, const bf16* __restrict__ lo,
                                          int c0, int ln, int quad,
                                          bf16x8 a0h, bf16x8 a1h, bf16x8 a0l, bf16x8 a1l) {
    bf16x8 b0h = *(const bf16x8*)(hi + (size_t)(c0 + ln) * 64 + quad * 8);
    bf16x8 b1h = *(const bf16x8*)(hi + (size_t)(c0 + ln) * 64 + 32 + quad * 8);
    bf16x8 b0l = *(const bf16x8*)(lo + (size_t)(c0 + ln) * 64 + quad * 8);
    bf16x8 b1l = *(const bf16x8*)(lo + (size_t)(c0 + ln) * 64 + 32 + quad * 8);
    f32x4 s = {0.f, 0.f, 0.f, 0.f};
    s = __builtin_amdgcn_mfma_f32_16x16x32_bf16(a0h, b0h, s, 0, 0, 0);
    s = __builtin_amdgcn_mfma_f32_16x16x32_bf16(a1h, b1h, s, 0, 0, 0);
    s = __builtin_amdgcn_mfma_f32_16x16x32_bf16(a0l, b0h, s, 0, 0, 0);
    s = __builtin_amdgcn_mfma_f32_16x16x32_bf16(a1l, b1h, s, 0, 0, 0);
    s = __builtin_amdgcn_mfma_f32_16x16x32_bf16(a0h, b0l, s, 0, 0, 0);
    s = __builtin_amdgcn_mfma_f32_16x16x32_bf16(a1h, b1l, s, 0, 0, 0);
    return s;
}

// fused two-pass masked attention per (head, 64-row block); 4 waves x 16 rows each
__launch_bounds__(256)
__global__ void k_attn(const bf16* __restrict__ hnhi, const bf16* __restrict__ hnlo,
                       const bf16* __restrict__ hthi, const bf16* __restrict__ htlo,
                       const unsigned int* __restrict__ mw,
                       const float* __restrict__ colmean,
                       float* __restrict__ hout) {
    __shared__ bf16 Plds[4][16 * 40];   // per-wave P tile, stride 40 breaks bank conflicts
    int head = blockIdx.y;
    int r0 = blockIdx.x * 64;
    int t = threadIdx.x;
    int w = t >> 6, lane = t & 63;
    int ln = lane & 15, quad = lane >> 4;
    int rw = r0 + w * 16;
    const bf16* hih = hnhi + (size_t)head * N * 64;
    const bf16* loh = hnlo + (size_t)head * N * 64;
    // A fragments (hi and lo) for this wave's 16 rows, k=0..31 and 32..63
    bf16x8 a0h = *(const bf16x8*)(hih + (size_t)(rw + ln) * 64 + quad * 8);
    bf16x8 a1h = *(const bf16x8*)(hih + (size_t)(rw + ln) * 64 + 32 + quad * 8);
    bf16x8 a0l = *(const bf16x8*)(loh + (size_t)(rw + ln) * 64 + quad * 8);
    bf16x8 a1l = *(const bf16x8*)(loh + (size_t)(rw + ln) * 64 + 32 + quad * 8);
    const unsigned int* mrow[4];
#pragma unroll
    for (int r = 0; r < 4; ++r) mrow[r] = mw + (size_t)(rw + quad * 4 + r) * 128;

    const float NEGINF = -__builtin_inff();
    float m4[4] = {NEGINF, NEGINF, NEGINF, NEGINF};

    // PASS A: masked row-max of raw cosine dot (monotone under /temp)
    for (int ct = 0; ct < 256; ++ct) {
        f32x4 s = sim_tile(hih, loh, ct << 4, ln, quad, a0h, a1h, a0l, a1l);
        int wi = ct >> 1;
        int sh = ((ct & 1) << 4) + ln;
#pragma unroll
        for (int r = 0; r < 4; ++r) {
            unsigned int bit = (mrow[r][wi] >> sh) & 1u;
            float v = bit ? s[r] : NEGINF;
            m4[r] = fmaxf(m4[r], v);
        }
    }
#pragma unroll
    for (int r = 0; r < 4; ++r) {
        float v = m4[r];
        v = fmaxf(v, __shfl_xor(v, 1, 64));
        v = fmaxf(v, __shfl_xor(v, 2, 64));
        v = fmaxf(v, __shfl_xor(v, 4, 64));
        v = fmaxf(v, __shfl_xor(v, 8, 64));
        m4[r] = v;
    }

    // PASS B: recompute (bit-identical), keep rule, exp, l and PV accumulation
    const bf16* thih = hthi + (size_t)head * N * 64;
    const bf16* tloh = htlo + (size_t)head * N * 64;
    float l4[4] = {0.f, 0.f, 0.f, 0.f};
    f32x4 pv[4];
#pragma unroll
    for (int nt = 0; nt < 4; ++nt) pv[nt] = (f32x4){0.f, 0.f, 0.f, 0.f};
    bf16* P = &Plds[w][0];
    for (int cp = 0; cp < 128; ++cp) {
#pragma unroll
        for (int tt = 0; tt < 2; ++tt) {
            int ct = cp * 2 + tt;
            f32x4 s = sim_tile(hih, loh, ct << 4, ln, quad, a0h, a1h, a0l, a1l);
            int wi = ct >> 1;
            int sh = ((ct & 1) << 4) + ln;
#pragma unroll
            for (int r = 0; r < 4; ++r) {
                unsigned int bit = (mrow[r][wi] >> sh) & 1u;
                bool keep = bit && (s[r] >= 0.5f * m4[r]);
                float arg = keep ? 5.0f * (s[r] - m4[r]) : NEGINF;
                float p = __expf(arg);
                bf16 pb = __float2bfloat16(p);
                l4[r] += __bfloat162float(pb);       // denominator from the ROUNDED p
                P[(quad * 4 + r) * 40 + tt * 16 + ln] = pb;
            }
        }
        __builtin_amdgcn_wave_barrier();
        bf16x8 pa = *(const bf16x8*)(P + ln * 40 + quad * 8);
        int cb = cp * 32;
#pragma unroll
        for (int nt = 0; nt < 4; ++nt) {
            bf16x8 bh = *(const bf16x8*)(thih + (size_t)(nt * 16 + ln) * N + cb + quad * 8);
            bf16x8 bl = *(const bf16x8*)(tloh + (size_t)(nt * 16 + ln) * N + cb + quad * 8);
            pv[nt] = __builtin_amdgcn_mfma_f32_16x16x32_bf16(pa, bh, pv[nt], 0, 0, 0);
            pv[nt] = __builtin_amdgcn_mfma_f32_16x16x32_bf16(pa, bl, pv[nt], 0, 0, 0);
        }
        __builtin_amdgcn_wave_barrier();
    }
#pragma unroll
    for (int r = 0; r < 4; ++r) {
        float v = l4[r];
        v += __shfl_xor(v, 1, 64);
        v += __shfl_xor(v, 2, 64);
        v += __shfl_xor(v, 4, 64);
        v += __shfl_xor(v, 8, 64);
        l4[r] = v;
    }
#pragma unroll
    for (int r = 0; r < 4; ++r) {
        int row = rw + quad * 4 + r;
        float lr = l4[r];
        float inv = (lr > 0.f) ? 1.0f / lr : 0.f;
#pragma unroll
        for (int nt = 0; nt < 4; ++nt) {
            int d = nt * 16 + ln;
            float v = (lr > 0.f) ? pv[nt][r] * inv : colmean[head * 64 + d];
            v = (v > 0.f) ? v : (__expf(v) - 1.0f);  // ELU
            hout[((size_t)head * N + row) * 64 + d] = v;
        }
    }
}

__global__ void k_combine(const float* __restrict__ hout, float* __restrict__ feat,
                          float* __restrict__ outp, int last) {
    int i = blockIdx.x * 256 + threadIdx.x;
    float v = 0.25f * (hout[i] + hout[i + N * 64] + hout[i + 2 * N * 64] + hout[i + 3 * N * 64]);
    if (last) outp[i] = v;
    else feat[i] = v;
}

extern "C" void kernel_launch(void* const* d_in, const int* in_sizes, int n_in,
                              void* d_out, int out_size, void* d_ws, size_t ws_size,
                              hipStream_t stream) {
    const float* features_in = (const float*)d_in[0];
    const int* adj = (const int*)d_in[1];
    const float* Ws = (const float*)d_in[2];
    char* ws = (char*)d_ws;
    unsigned int* mw = (unsigned int*)(ws + OFF_MASK);
    float* feat = (float*)(ws + OFF_FEAT);
    bf16* hnhi = (bf16*)(ws + OFF_HNHI);
    bf16* hnlo = (bf16*)(ws + OFF_HNLO);
    bf16* hthi = (bf16*)(ws + OFF_HTHI);
    bf16* htlo = (bf16*)(ws + OFF_HTLO);
    float* hout = (float*)(ws + OFF_HOUT);
    float* cm = (float*)(ws + OFF_CM);

    k_packadj<<<dim3(NSTEP * N / 4), dim3(256), 0, stream>>>(adj, mw);
    for (int s = 0; s < NSTEP; ++s) {
        hipMemsetAsync(cm, 0, NH * D * sizeof(float), stream);
        const float* X = (s == 0) ? features_in : feat;
        k_phase0<<<dim3(64, NH), dim3(256), 0, stream>>>(X, Ws + (size_t)s * NH * D * D,
                                                         hnhi, hnlo, hthi, htlo, cm);
        k_attn<<<dim3(64, NH), dim3(256), 0, stream>>>(hnhi, hnlo, hthi, htlo,
                                                       mw + (size_t)s * N * 128, cm, hout);
        k_combine<<<dim3(N * D / 256), dim3(256), 0, stream>>>(hout, feat, (float*)d_out, s == NSTEP - 1);
    }
}

// Round 3
// 1878.152 us; speedup vs baseline: 1.2427x; 1.2427x over previous
//
#include <hip/hip_runtime.h>
#include <hip/hip_bf16.h>

#define N 4096
#define D 64
#define NH 4
#define NSTEP 4

typedef short bf16x8 __attribute__((ext_vector_type(8)));
typedef float f32x4 __attribute__((ext_vector_type(4)));
typedef __hip_bfloat16 bf16;

// ws layout (bytes)
static const size_t OFF_MASK = 0;                              // NSTEP*N*128 u32 = 8 MB
static const size_t OFF_FEAT = (size_t)8 << 20;                // N*D f32 = 1 MB
static const size_t OFF_HNHI = (size_t)9 << 20;                // NH*N*D bf16 = 2 MB
static const size_t OFF_HNLO = (size_t)11 << 20;               // 2 MB
static const size_t OFF_HTHI = (size_t)13 << 20;               // 2 MB
static const size_t OFF_HTLO = (size_t)15 << 20;               // 2 MB
static const size_t OFF_HOUT = (size_t)17 << 20;               // NH*N*D f32 = 4 MB
static const size_t OFF_CM   = (size_t)21 << 20;               // NH*D f32

// one wave packs one row (4096 ints -> 128 u32 of bits), rows = NSTEP*N
__global__ void k_packadj(const int* __restrict__ adj, unsigned int* __restrict__ mw) {
    int wid = blockIdx.x * 4 + (threadIdx.x >> 6);
    int lane = threadIdx.x & 63;
    const int* rowp = adj + (size_t)wid * N;
    unsigned long long* out = (unsigned long long*)(mw + (size_t)wid * 128);
    for (int i = 0; i < 64; ++i) {
        int v = rowp[i * 64 + lane];
        unsigned long long b = __ballot(v > 0);
        if (lane == 0) out[i] = b;
    }
}

// h = X @ W[head] in fp32; emit hi/lo bf16 splits of hn (row-normalized) and of h (transposed);
// accumulate per-head column mean of h (fp32) for the empty-keep fallback.
__global__ void k_phase0(const float* __restrict__ X, const float* __restrict__ W,
                         bf16* __restrict__ hnhi, bf16* __restrict__ hnlo,
                         bf16* __restrict__ hthi, bf16* __restrict__ htlo,
                         float* __restrict__ colmean) {
    __shared__ float Xs[64][65];
    __shared__ float Wsh[64][64];
    __shared__ float colsum[64];
    int head = blockIdx.y;
    int r0 = blockIdx.x * 64;
    int t = threadIdx.x;
    for (int i = 0; i < 16; ++i) {
        int idx = t + 256 * i;
        int r = idx >> 6, c = idx & 63;
        Xs[r][c] = X[(size_t)(r0 + r) * 64 + c];
        Wsh[r][c] = W[(size_t)head * 4096 + idx];
    }
    if (t < 64) colsum[t] = 0.f;
    __syncthreads();
    int lane = t & 63, w = t >> 6;
    int lr = w * 16 + (lane >> 2);
    int e0 = (lane & 3) * 16;
    float acc[16];
#pragma unroll
    for (int j = 0; j < 16; ++j) acc[j] = 0.f;
    for (int d = 0; d < 64; ++d) {
        float xv = Xs[lr][d];
#pragma unroll
        for (int j = 0; j < 16; ++j) acc[j] = fmaf(xv, Wsh[d][e0 + j], acc[j]);
    }
    float ss = 0.f;
#pragma unroll
    for (int j = 0; j < 16; ++j) ss = fmaf(acc[j], acc[j], ss);
    ss += __shfl_xor(ss, 1, 64);
    ss += __shfl_xor(ss, 2, 64);
    float rn = 1.0f / (sqrtf(ss) + 1e-12f);
    int row = r0 + lr;
#pragma unroll
    for (int j = 0; j < 16; ++j) {
        float hv = acc[j];
        bf16 hhi = __float2bfloat16(hv);
        bf16 hlo = __float2bfloat16(hv - __bfloat162float(hhi));
        size_t tidx = (size_t)head * N * 64 + (size_t)(e0 + j) * N + row;
        hthi[tidx] = hhi;
        htlo[tidx] = hlo;
        float hnv = hv * rn;
        bf16 nhi = __float2bfloat16(hnv);
        bf16 nlo = __float2bfloat16(hnv - __bfloat162float(nhi));
        size_t nidx = ((size_t)head * N + row) * 64 + e0 + j;
        hnhi[nidx] = nhi;
        hnlo[nidx] = nlo;
    }
#pragma unroll
    for (int j = 0; j < 16; ++j) {
        float v = acc[j];
        v += __shfl_xor(v, 4, 64);
        v += __shfl_xor(v, 8, 64);
        v += __shfl_xor(v, 16, 64);
        v += __shfl_xor(v, 32, 64);
        if ((lane >> 2) == 0) atomicAdd(&colsum[e0 + j], v);
    }
    __syncthreads();
    if (t < 64) atomicAdd(&colmean[head * 64 + t], colsum[t] * (1.0f / N));
}

struct BFrag { bf16x8 h0, h1, l0, l1; };

__device__ __forceinline__ BFrag load_bfrag(const bf16* __restrict__ hih,
                                            const bf16* __restrict__ loh,
                                            int ct, int ln, int quad) {
    BFrag f;
    const bf16* ph = hih + (size_t)((ct << 4) + ln) * 64 + quad * 8;
    const bf16* pl = loh + (size_t)((ct << 4) + ln) * 64 + quad * 8;
    f.h0 = *(const bf16x8*)(ph);
    f.h1 = *(const bf16x8*)(ph + 32);
    f.l0 = *(const bf16x8*)(pl);
    f.l1 = *(const bf16x8*)(pl + 32);
    return f;
}

// split-bf16 sim: s = hi*hi + lo*hi + hi*lo (fp32 accumulate); identical sequence in
// both passes so the keep rule compares bit-identical values.
__device__ __forceinline__ f32x4 sim_mfma(const BFrag& b,
                                          bf16x8 a0h, bf16x8 a1h, bf16x8 a0l, bf16x8 a1l) {
    f32x4 s = {0.f, 0.f, 0.f, 0.f};
    s = __builtin_amdgcn_mfma_f32_16x16x32_bf16(a0h, b.h0, s, 0, 0, 0);
    s = __builtin_amdgcn_mfma_f32_16x16x32_bf16(a1h, b.h1, s, 0, 0, 0);
    s = __builtin_amdgcn_mfma_f32_16x16x32_bf16(a0l, b.h0, s, 0, 0, 0);
    s = __builtin_amdgcn_mfma_f32_16x16x32_bf16(a1l, b.h1, s, 0, 0, 0);
    s = __builtin_amdgcn_mfma_f32_16x16x32_bf16(a0h, b.l0, s, 0, 0, 0);
    s = __builtin_amdgcn_mfma_f32_16x16x32_bf16(a1h, b.l1, s, 0, 0, 0);
    return s;
}

// fused two-pass masked attention. Block = 16 rows of one head; 4 waves split the
// 4096 columns (1024 each) for BOTH passes; cross-wave reduction via LDS.
__launch_bounds__(256, 4)
__global__ void k_attn(const bf16* __restrict__ hnhi, const bf16* __restrict__ hnlo,
                       const bf16* __restrict__ hthi, const bf16* __restrict__ htlo,
                       const unsigned int* __restrict__ mw,
                       const float* __restrict__ colmean,
                       float* __restrict__ hout) {
    __shared__ bf16 Plds[4][16 * 40];      // per-wave P tile (16 rows x 32 cols, stride 40)
    __shared__ float maxb[4][16];
    __shared__ float lbuf[4][16];
    __shared__ float pvbuf[4][16][66];     // per-wave PV partials, padded stride
    int head = blockIdx.y;
    int rw = blockIdx.x * 16;
    int t = threadIdx.x;
    int w = t >> 6, lane = t & 63;
    int ln = lane & 15, quad = lane >> 4;
    const bf16* hih = hnhi + (size_t)head * N * 64;
    const bf16* loh = hnlo + (size_t)head * N * 64;
    // A fragments (hi and lo) for the block's 16 rows, k=0..31 and 32..63
    bf16x8 a0h = *(const bf16x8*)(hih + (size_t)(rw + ln) * 64 + quad * 8);
    bf16x8 a1h = *(const bf16x8*)(hih + (size_t)(rw + ln) * 64 + 32 + quad * 8);
    bf16x8 a0l = *(const bf16x8*)(loh + (size_t)(rw + ln) * 64 + quad * 8);
    bf16x8 a1l = *(const bf16x8*)(loh + (size_t)(rw + ln) * 64 + 32 + quad * 8);
    const unsigned int* mrow[4];
#pragma unroll
    for (int r = 0; r < 4; ++r) mrow[r] = mw + (size_t)(rw + quad * 4 + r) * 128;

    const float NEGINF = -__builtin_inff();
    float m4[4] = {NEGINF, NEGINF, NEGINF, NEGINF};
    int ct0 = w * 64;   // this wave's 64 column tiles (1024 columns)

    // PASS A: masked row-max of raw cosine dot over this wave's columns
    {
        BFrag cur = load_bfrag(hih, loh, ct0, ln, quad);
        for (int i = 0; i < 64; ++i) {
            BFrag nxt;
            if (i < 63) nxt = load_bfrag(hih, loh, ct0 + i + 1, ln, quad);
            f32x4 s = sim_mfma(cur, a0h, a1h, a0l, a1l);
            int ct = ct0 + i;
            int wi = ct >> 1;
            int sh = ((ct & 1) << 4) + ln;
#pragma unroll
            for (int r = 0; r < 4; ++r) {
                unsigned int bit = (mrow[r][wi] >> sh) & 1u;
                float v = bit ? s[r] : NEGINF;
                m4[r] = fmaxf(m4[r], v);
            }
            cur = nxt;
        }
    }
#pragma unroll
    for (int r = 0; r < 4; ++r) {
        float v = m4[r];
        v = fmaxf(v, __shfl_xor(v, 1, 64));
        v = fmaxf(v, __shfl_xor(v, 2, 64));
        v = fmaxf(v, __shfl_xor(v, 4, 64));
        v = fmaxf(v, __shfl_xor(v, 8, 64));
        if (ln == 0) maxb[w][quad * 4 + r] = v;
    }
    __syncthreads();
#pragma unroll
    for (int r = 0; r < 4; ++r) {
        int row = quad * 4 + r;
        m4[r] = fmaxf(fmaxf(maxb[0][row], maxb[1][row]), fmaxf(maxb[2][row], maxb[3][row]));
    }

    // PASS B: recompute (bit-identical), keep rule, exp, partial l and partial PV
    const bf16* thih = hthi + (size_t)head * N * 64;
    const bf16* tloh = htlo + (size_t)head * N * 64;
    float l4[4] = {0.f, 0.f, 0.f, 0.f};
    f32x4 pv[4];
#pragma unroll
    for (int nt = 0; nt < 4; ++nt) pv[nt] = (f32x4){0.f, 0.f, 0.f, 0.f};
    bf16* P = &Plds[w][0];
    {
        BFrag cur = load_bfrag(hih, loh, ct0, ln, quad);
        for (int cp = 0; cp < 32; ++cp) {
#pragma unroll
            for (int tt = 0; tt < 2; ++tt) {
                int i = cp * 2 + tt;
                BFrag nxt;
                if (i < 63) nxt = load_bfrag(hih, loh, ct0 + i + 1, ln, quad);
                f32x4 s = sim_mfma(cur, a0h, a1h, a0l, a1l);
                int ct = ct0 + i;
                int wi = ct >> 1;
                int sh = ((ct & 1) << 4) + ln;
#pragma unroll
                for (int r = 0; r < 4; ++r) {
                    unsigned int bit = (mrow[r][wi] >> sh) & 1u;
                    bool keep = bit && (s[r] >= 0.5f * m4[r]);
                    float arg = keep ? 5.0f * (s[r] - m4[r]) : NEGINF;
                    float p = __expf(arg);
                    bf16 pb = __float2bfloat16(p);
                    l4[r] += __bfloat162float(pb);   // denominator from the ROUNDED p
                    P[(quad * 4 + r) * 40 + tt * 16 + ln] = pb;
                }
                cur = nxt;
            }
            __builtin_amdgcn_wave_barrier();
            bf16x8 pa = *(const bf16x8*)(P + ln * 40 + quad * 8);
            int cb = ct0 * 16 + cp * 32;
#pragma unroll
            for (int nt = 0; nt < 4; ++nt) {
                bf16x8 bh = *(const bf16x8*)(thih + (size_t)(nt * 16 + ln) * N + cb + quad * 8);
                bf16x8 bl = *(const bf16x8*)(tloh + (size_t)(nt * 16 + ln) * N + cb + quad * 8);
                pv[nt] = __builtin_amdgcn_mfma_f32_16x16x32_bf16(pa, bh, pv[nt], 0, 0, 0);
                pv[nt] = __builtin_amdgcn_mfma_f32_16x16x32_bf16(pa, bl, pv[nt], 0, 0, 0);
            }
            __builtin_amdgcn_wave_barrier();
        }
    }
    // per-wave partials -> LDS
#pragma unroll
    for (int r = 0; r < 4; ++r) {
        float v = l4[r];
        v += __shfl_xor(v, 1, 64);
        v += __shfl_xor(v, 2, 64);
        v += __shfl_xor(v, 4, 64);
        v += __shfl_xor(v, 8, 64);
        if (ln == 0) lbuf[w][quad * 4 + r] = v;
    }
#pragma unroll
    for (int nt = 0; nt < 4; ++nt)
#pragma unroll
        for (int r = 0; r < 4; ++r)
            pvbuf[w][quad * 4 + r][nt * 16 + ln] = pv[nt][r];
    __syncthreads();

    // epilogue: reduce over waves, normalize, ELU, store (float4 per thread)
    int row = t >> 4;
    int c4 = (t & 15) * 4;
    float lsum = lbuf[0][row] + lbuf[1][row] + lbuf[2][row] + lbuf[3][row];
    float inv = (lsum > 0.f) ? 1.0f / lsum : 0.f;
    float4 o;
    float* op = &o.x;
#pragma unroll
    for (int i = 0; i < 4; ++i) {
        int col = c4 + i;
        float v = pvbuf[0][row][col] + pvbuf[1][row][col] + pvbuf[2][row][col] + pvbuf[3][row][col];
        v = (lsum > 0.f) ? v * inv : colmean[head * 64 + col];
        op[i] = (v > 0.f) ? v : (__expf(v) - 1.0f);
    }
    *(float4*)(hout + ((size_t)head * N + rw + row) * 64 + c4) = o;
}

__global__ void k_combine(const float* __restrict__ hout, float* __restrict__ feat,
                          float* __restrict__ outp, int last) {
    int i = blockIdx.x * 256 + threadIdx.x;
    float v = 0.25f * (hout[i] + hout[i + N * 64] + hout[i + 2 * N * 64] + hout[i + 3 * N * 64]);
    if (last) outp[i] = v;
    else feat[i] = v;
}

extern "C" void kernel_launch(void* const* d_in, const int* in_sizes, int n_in,
                              void* d_out, int out_size, void* d_ws, size_t ws_size,
                              hipStream_t stream) {
    const float* features_in = (const float*)d_in[0];
    const int* adj = (const int*)d_in[1];
    const float* Ws = (const float*)d_in[2];
    char* ws = (char*)d_ws;
    unsigned int* mw = (unsigned int*)(ws + OFF_MASK);
    float* feat = (float*)(ws + OFF_FEAT);
    bf16* hnhi = (bf16*)(ws + OFF_HNHI);
    bf16* hnlo = (bf16*)(ws + OFF_HNLO);
    bf16* hthi = (bf16*)(ws + OFF_HTHI);
    bf16* htlo = (bf16*)(ws + OFF_HTLO);
    float* hout = (float*)(ws + OFF_HOUT);
    float* cm = (float*)(ws + OFF_CM);

    k_packadj<<<dim3(NSTEP * N / 4), dim3(256), 0, stream>>>(adj, mw);
    for (int s = 0; s < NSTEP; ++s) {
        hipMemsetAsync(cm, 0, NH * D * sizeof(float), stream);
        const float* X = (s == 0) ? features_in : feat;
        k_phase0<<<dim3(64, NH), dim3(256), 0, stream>>>(X, Ws + (size_t)s * NH * D * D,
                                                         hnhi, hnlo, hthi, htlo, cm);
        k_attn<<<dim3(N / 16, NH), dim3(256), 0, stream>>>(hnhi, hnlo, hthi, htlo,
                                                           mw + (size_t)s * N * 128, cm, hout);
        k_combine<<<dim3(N * D / 256), dim3(256), 0, stream>>>(hout, feat, (float*)d_out, s == NSTEP - 1);
    }
}